// Round 1
// baseline (912.229 us; speedup 1.0000x reference)
//
#include <hip/hip_runtime.h>

#define GH 14
#define GW 14
#define CCHUNK 64   // channels per block; C=256 -> 4 chunks per box

__global__ __launch_bounds__(256) void roi_align_kernel(
    const float* __restrict__ fmap,
    const float* __restrict__ rois,
    const int*   __restrict__ imgh,
    float*       __restrict__ out,
    int C, int H, int W)
{
    const int t = threadIdx.x;
    if (t >= GH * GW) return;          // 196 active lanes; no LDS, no sync needed

    const int m  = blockIdx.y;         // box index (wave-uniform)
    const int c0 = blockIdx.x * CCHUNK;

    // sample position within the 14x14 grid — computed ONCE per 64 channels
    const int j = t % GW;
    const int i = t / GW;

    const float stride = (float)imgh[0] / (float)H;   // 800/200 = 4.0

    const float* r = rois + (size_t)m * 6;            // m uniform -> scalar loads
    const int   b  = (int)r[0];
    const float x1 = r[2] / stride;
    const float y1 = r[3] / stride;
    const float x2 = r[4] / stride;
    const float y2 = r[5] / stride;

    const float ti = (float)i / (float)(GH - 1);
    const float tj = (float)j / (float)(GW - 1);
    const float ys = y1 + (y2 - y1) * ti;
    const float xs = x1 + (x2 - x1) * tj;

    const bool my = (ys >= 0.0f) && (ys <= (float)(H - 1));
    const bool mx = (xs >= 0.0f) && (xs <= (float)(W - 1));

    const float y0f = floorf(ys);
    const float x0f = floorf(xs);
    const float ly  = ys - y0f;
    const float lx  = xs - x0f;

    const int y0  = (int)fminf(fmaxf(y0f,        0.0f), (float)(H - 1));
    const int y1i = (int)fminf(fmaxf(y0f + 1.0f, 0.0f), (float)(H - 1));
    const int x0  = (int)fminf(fmaxf(x0f,        0.0f), (float)(W - 1));
    const int x1i = (int)fminf(fmaxf(x0f + 1.0f, 0.0f), (float)(W - 1));

    // fold the out-of-bounds mask into the weights: no per-channel select
    const float msk = (my && mx) ? 1.0f : 0.0f;
    const float w00 = msk * (1.0f - ly) * (1.0f - lx);
    const float w01 = msk * (1.0f - ly) * lx;
    const float w10 = msk * ly * (1.0f - lx);
    const float w11 = msk * ly * lx;

    const int o00 = y0  * W + x0;
    const int o01 = y0  * W + x1i;
    const int o10 = y1i * W + x0;
    const int o11 = y1i * W + x1i;

    const int HW = H * W;
    // plane base is wave-uniform (b, c0 uniform) -> SGPR base + 32-bit lane offsets
    const float* __restrict__ p = fmap + ((size_t)b * C + c0) * (size_t)HW;
    float*       __restrict__ o = out  + ((size_t)m * C + c0) * (size_t)(GH * GW) + t;

    #pragma unroll 4
    for (int c = 0; c < CCHUNK; ++c) {
        const float g00 = p[o00];
        const float g01 = p[o01];
        const float g10 = p[o10];
        const float g11 = p[o11];
        *o = g00 * w00 + g01 * w01 + g10 * w10 + g11 * w11;
        p += HW;            // next channel plane (scalar add)
        o += GH * GW;       // next channel in output (coalesced store)
    }
}

extern "C" void kernel_launch(void* const* d_in, const int* in_sizes, int n_in,
                              void* d_out, int out_size, void* d_ws, size_t ws_size,
                              hipStream_t stream) {
    const float* fmap = (const float*)d_in[0];   // [N=4, C=256, H=200, W=200]
    const float* rois = (const float*)d_in[1];   // [M, 6] (n, score, x1, y1, x2, y2)
    const int*   imgh = (const int*)d_in[2];     // scalar 800

    float* out = (float*)d_out;

    const int C = 256, H = 200, W = 200;
    const int M = in_sizes[1] / 6;               // 2048

    dim3 grid(C / CCHUNK, M);                    // (4, 2048)
    roi_align_kernel<<<grid, 256, 0, stream>>>(fmap, rois, imgh, out, C, H, W);
}

// Round 2
// 737.920 us; speedup vs baseline: 1.2362x; 1.2362x over previous
//
#include <hip/hip_runtime.h>

#define GH 14
#define GW 14

// ---------------- kernel 1: NCHW -> NHWC transpose (per batch [C,HW] -> [HW,C]) ----
__global__ __launch_bounds__(256) void nchw_to_nhwc_kernel(
    const float* __restrict__ src, float* __restrict__ dst, int C, int HW)
{
    __shared__ float tile[32][33];               // +1 pad: conflict-free transpose
    const int b  = blockIdx.z;
    const int p0 = blockIdx.x * 32;              // HW tile (40000 % 32 == 0)
    const int c0 = blockIdx.y * 32;              // C tile  (256 % 32 == 0)
    const int tx = threadIdx.x;                  // 0..31
    const int ty = threadIdx.y;                  // 0..7
    const float* s = src + (size_t)b * C * HW;
    float*       d = dst + (size_t)b * C * HW;
    #pragma unroll
    for (int k = 0; k < 4; ++k)                  // read coalesced along HW
        tile[ty + k * 8][tx] = s[(size_t)(c0 + ty + k * 8) * HW + p0 + tx];
    __syncthreads();
    #pragma unroll
    for (int k = 0; k < 4; ++k)                  // write coalesced along C
        d[(size_t)(p0 + ty + k * 8) * C + c0 + tx] = tile[tx][ty + k * 8];
}

// ---------------- kernel 2: gather from NHWC, transpose through LDS ---------------
__global__ __launch_bounds__(256) void roi_gather_nhwc_kernel(
    const float* __restrict__ fmapT,   // [N, H, W, C]
    const float* __restrict__ rois,
    const int*   __restrict__ imgh,
    float*       __restrict__ out,     // [M, C, GH, GW]
    int C, int H, int W)
{
    __shared__ float lds[64 * 197];    // [64 ch][196 s], stride 197 -> conflict-free
    const int tid  = threadIdx.x;
    const int lane = tid & 63;         // = channel within chunk
    const int wv   = tid >> 6;         // wave 0..3, owns samples [49*wv, 49*wv+49)
    const int m    = blockIdx.y;
    const int c0   = blockIdx.x * 64;

    const float stride = (float)imgh[0] / (float)H;
    const float* r = rois + (size_t)m * 6;
    const int   b   = (int)r[0];
    const float rx1 = r[2] / stride;
    const float ry1 = r[3] / stride;
    const float rx2 = r[4] / stride;
    const float ry2 = r[5] / stride;

    // wave-uniform plane base; per-lane channel offset
    const float* __restrict__ base = fmapT + (size_t)b * H * W * C + c0 + lane;

    const float fH = (float)(H - 1), fW = (float)(W - 1);

    #pragma unroll 2
    for (int k = 0; k < 49; ++k) {
        const int s = wv * 49 + k;                 // wave-uniform sample index
        const int i = s / GW;
        const int j = s - i * GW;

        const float ys = ry1 + (ry2 - ry1) * ((float)i / (float)(GH - 1));
        const float xs = rx1 + (rx2 - rx1) * ((float)j / (float)(GW - 1));

        const bool my = (ys >= 0.0f) && (ys <= fH);
        const bool mx = (xs >= 0.0f) && (xs <= fW);

        const float y0f = floorf(ys);
        const float x0f = floorf(xs);
        const float ly  = ys - y0f;
        const float lx  = xs - x0f;

        const int y0  = (int)fminf(fmaxf(y0f,        0.0f), fH);
        const int y1i = (int)fminf(fmaxf(y0f + 1.0f, 0.0f), fH);
        const int x0  = (int)fminf(fmaxf(x0f,        0.0f), fW);
        const int x1i = (int)fminf(fmaxf(x0f + 1.0f, 0.0f), fW);

        const float msk = (my && mx) ? 1.0f : 0.0f;
        const float w00 = msk * (1.0f - ly) * (1.0f - lx);
        const float w01 = msk * (1.0f - ly) * lx;
        const float w10 = msk * ly * (1.0f - lx);
        const float w11 = msk * ly * lx;

        // four fully-coalesced 256B loads (each exactly 4 cache lines, aligned)
        const int o00 = (y0  * W + x0 ) * C;
        const int o01 = (y0  * W + x1i) * C;
        const int o10 = (y1i * W + x0 ) * C;
        const int o11 = (y1i * W + x1i) * C;
        const float g00 = base[o00];
        const float g01 = base[o01];
        const float g10 = base[o10];
        const float g11 = base[o11];

        lds[lane * 197 + s] = g00 * w00 + g01 * w01 + g10 * w10 + g11 * w11;
    }
    __syncthreads();

    // transposed write-out: consecutive threads -> consecutive samples (coalesced)
    for (int k = tid; k < 64 * GH * GW; k += 256) {
        const int ch = k / (GH * GW);
        const int s  = k - ch * (GH * GW);
        out[((size_t)m * C + c0 + ch) * (GH * GW) + s] = lds[ch * 197 + s];
    }
}

// ---------------- fallback: round-1 kernel (used only if workspace too small) -----
#define CCHUNK 64
__global__ __launch_bounds__(256) void roi_align_fallback(
    const float* __restrict__ fmap, const float* __restrict__ rois,
    const int* __restrict__ imgh, float* __restrict__ out, int C, int H, int W)
{
    const int t = threadIdx.x;
    if (t >= GH * GW) return;
    const int m = blockIdx.y;
    const int c0 = blockIdx.x * CCHUNK;
    const int j = t % GW;
    const int i = t / GW;
    const float stride = (float)imgh[0] / (float)H;
    const float* r = rois + (size_t)m * 6;
    const int b = (int)r[0];
    const float x1 = r[2] / stride, y1 = r[3] / stride;
    const float x2 = r[4] / stride, y2 = r[5] / stride;
    const float ys = y1 + (y2 - y1) * ((float)i / (float)(GH - 1));
    const float xs = x1 + (x2 - x1) * ((float)j / (float)(GW - 1));
    const bool my = (ys >= 0.0f) && (ys <= (float)(H - 1));
    const bool mx = (xs >= 0.0f) && (xs <= (float)(W - 1));
    const float y0f = floorf(ys), x0f = floorf(xs);
    const float ly = ys - y0f, lx = xs - x0f;
    const int y0  = (int)fminf(fmaxf(y0f,        0.0f), (float)(H - 1));
    const int y1i = (int)fminf(fmaxf(y0f + 1.0f, 0.0f), (float)(H - 1));
    const int x0  = (int)fminf(fmaxf(x0f,        0.0f), (float)(W - 1));
    const int x1i = (int)fminf(fmaxf(x0f + 1.0f, 0.0f), (float)(W - 1));
    const float msk = (my && mx) ? 1.0f : 0.0f;
    const float w00 = msk * (1.0f - ly) * (1.0f - lx);
    const float w01 = msk * (1.0f - ly) * lx;
    const float w10 = msk * ly * (1.0f - lx);
    const float w11 = msk * ly * lx;
    const int o00 = y0 * W + x0, o01 = y0 * W + x1i;
    const int o10 = y1i * W + x0, o11 = y1i * W + x1i;
    const int HW = H * W;
    const float* __restrict__ p = fmap + ((size_t)b * C + c0) * (size_t)HW;
    float* __restrict__ o = out + ((size_t)m * C + c0) * (size_t)(GH * GW) + t;
    #pragma unroll 4
    for (int c = 0; c < CCHUNK; ++c) {
        const float g00 = p[o00], g01 = p[o01], g10 = p[o10], g11 = p[o11];
        *o = g00 * w00 + g01 * w01 + g10 * w10 + g11 * w11;
        p += HW; o += GH * GW;
    }
}

extern "C" void kernel_launch(void* const* d_in, const int* in_sizes, int n_in,
                              void* d_out, int out_size, void* d_ws, size_t ws_size,
                              hipStream_t stream) {
    const float* fmap = (const float*)d_in[0];   // [4, 256, 200, 200]
    const float* rois = (const float*)d_in[1];   // [M, 6]
    const int*   imgh = (const int*)d_in[2];     // scalar 800
    float* out = (float*)d_out;

    const int C = 256, H = 200, W = 200, N = 4;
    const int M  = in_sizes[1] / 6;              // 2048
    const int HW = H * W;

    const size_t need = (size_t)N * C * HW * sizeof(float);  // 163.84 MB
    if (ws_size >= need) {
        float* fmapT = (float*)d_ws;
        dim3 tgrid(HW / 32, C / 32, N);          // 40000/32 = 1250 exact
        nchw_to_nhwc_kernel<<<tgrid, dim3(32, 8), 0, stream>>>(fmap, fmapT, C, HW);
        dim3 ggrid(C / 64, M);                   // (4, 2048)
        roi_gather_nhwc_kernel<<<ggrid, 256, 0, stream>>>(fmapT, rois, imgh, out, C, H, W);
    } else {
        dim3 grid(C / CCHUNK, M);
        roi_align_fallback<<<grid, 256, 0, stream>>>(fmap, rois, imgh, out, C, H, W);
    }
}